// Round 15
// baseline (223.508 us; speedup 1.0000x reference)
//
#include <hip/hip_runtime.h>
#include <hip/hip_bf16.h>

#define NN 50000      // nodes
#define NE 800000     // edges
#define NR 500        // relations
#define KEH 256       // input feat dim
#define KRH 128       // proj feat dim
#define NSB 8         // node super-bins (node / 6250), aligned to 8 XCDs
#define SBW 6250      // super-bin width
#define NBK (NR*NSB)  // 4000 buckets
#define NBE 256       // edge-pass blocks (k_edge / k_mkrec)
#define EPB (NE/NBE)  // 3125 edges per block
#define NTILE 3125    // 16-row GEMM tiles (50000/16 exactly)
#define CSB 16        // k_scan bins per slice (NBK/CSB = 250 slices/pass)

typedef __attribute__((ext_vector_type(8))) __bf16 bf16x8;
typedef __attribute__((ext_vector_type(4))) float f32x4;

// ---- workspace layout (bytes, 16B aligned), total ~50.6 MiB ----
#define OFF_XH     0UL            // [NN][128] bf16
#define OFF_XT     12800000UL     // [NN][128] bf16
#define OFF_SP     25600000UL     // [NN] float4
#define OFF_DP     26400000UL     // [NN] float4
#define OFF_SUMS   27200000UL     // [NR*4] f32 (8000 B)
#define OFF_HISTH  27208000UL     // [NBK] u32 totals (16000 B)
#define OFF_HISTT  27224000UL     // [NBK] u32 totals (16000 B)
// zero region SUMS..HISTT = 40000 B = 10000 u32
#define OFF_INVS   27240000UL     // [NR*4] f32
#define OFF_BASEH  27248000UL     // [NBK+1] u32 (16016 B)
#define OFF_BASET  27264016UL     // [NBK+1] u32
#define OFF_RECH   27312032UL     // [NE] uint2 (node, w1) 6.4 MB
#define OFF_RECT   33712032UL     // [NE] uint2 (node, w2) 6.4 MB
#define OFF_PART   40112032UL     // [NBK][128] f32 partials (2.048 MB)
#define OFF_AH     42160032UL     // [256] f32
#define OFF_AT     42161056UL     // [256] f32
#define OFF_FLAG   42162080UL     // u32
#define OFF_WHH    42162144UL     // [128][256] bf16, FRAGMENT order
#define OFF_WTH    42293216UL
#define OFF_HPBH   42424288UL     // [NBE][NBK] u32 per-block hist/offsets 4.096 MB
#define OFF_HPBT   46520288UL     // [NBE][NBK] u32                       4.096 MB
// end 50,616,288

__device__ __forceinline__ int clampi(int v, int hi) {  // [0, hi)
    v = v < 0 ? 0 : v;
    return v >= hi ? hi - 1 : v;
}

// Wave-replicated dtype sniff (see round-8 notes).
__device__ __forceinline__ int sniff_isbf(const unsigned* xe_raw) {
    int lane = threadIdx.x & 63;
    unsigned w = xe_raw[lane];
    unsigned ex = (w >> 7) & 0xFFu;
    bool hit = (ex >= 115u && ex <= 131u);
    return __popcll(__ballot(hit)) >= 32;
}

// block 0: flag + a_h/a_t convert. blocks 1..128: weight -> FRAGMENT order
// (bf16 cast). blocks 129+: zero sums + histH + histT (10000 u32).
// Frag order: out index o = ((ct*8+ks)*64 + q*16 + c)*8 + e  holds
// w[ct*16+c][ks*32+q*8+e]  — lane l=q*16+c of fragment (ct,ks) reads its
// 8 contiguous bf16 (col=l&15, k-seg=(l>>4)*8) as one 16B chunk; the LDS
// stage is a linear 64KB copy.
__global__ __launch_bounds__(256) void k_init(const unsigned* __restrict__ xe_raw,
                                              const void* __restrict__ ah_in, const void* __restrict__ at_in,
                                              const void* __restrict__ wh, const void* __restrict__ wt,
                                              unsigned* __restrict__ flag, float* __restrict__ ah32,
                                              float* __restrict__ at32,
                                              __bf16* __restrict__ whh, __bf16* __restrict__ wth,
                                              unsigned* __restrict__ zero1) {
    int isbf = sniff_isbf(xe_raw);
    int t = threadIdx.x;
    if (blockIdx.x == 0) {
        if (t == 0) flag[0] = (unsigned)isbf;
        ah32[t] = isbf ? __bfloat162float(((const __hip_bfloat16*)ah_in)[t]) : ((const float*)ah_in)[t];
        at32[t] = isbf ? __bfloat162float(((const __hip_bfloat16*)at_in)[t]) : ((const float*)at_in)[t];
    } else if (blockIdx.x <= 128) {
        int o = (blockIdx.x - 1) * 256 + t;   // [0, 32768) frag-order output idx
        int e = o & 7, c = (o >> 3) & 15, q = (o >> 7) & 3, ks = (o >> 9) & 7, ct = o >> 12;
        int i = (ct * 16 + c) * KEH + ks * 32 + q * 8 + e;   // row-major source
        if (isbf) {
            whh[o] = ((const __bf16*)wh)[i];
            wth[o] = ((const __bf16*)wt)[i];
        } else {
            whh[o] = (__bf16)((const float*)wh)[i];
            wth[o] = (__bf16)((const float*)wt)[i];
        }
    } else {
        int stride = (gridDim.x - 129) * 256;
        for (int i = (blockIdx.x - 129) * 256 + t; i < 10000; i += stride) zero1[i] = 0u;
    }
}

// One-pass both-phase GEMM + fused per-node scores, single-term bf16 MFMA.
// Round-15: 1024 thr (16 waves = 4/SIMD — round-14's (512,2) config ran at
// 2 waves/SIMD, 16% occupancy, pure exposed latency at 44.5us vs 8.7us
// memory floor). Grid 196 (196*16 = 3136 wave-slots >= 3125 tiles), ONE
// tile per wave. Both fragment-order weight matrices staged into LDS once
// per block (128 KB -> 1 block/CU); xe read ONCE (both phases per tile).
// VGPR 112 fits the 128-cap of launch_bounds(1024,4) — WRITE staying
// ~27 MB is the no-spill check.
__global__ __launch_bounds__(1024, 4) void k_gemm(const void* __restrict__ xe,
                                              const unsigned* __restrict__ flag,
                                              const __bf16* __restrict__ whh, const __bf16* __restrict__ wth,
                                              const float* __restrict__ ah, const float* __restrict__ at,
                                              __hip_bfloat16* __restrict__ xh, __hip_bfloat16* __restrict__ xt,
                                              float4* __restrict__ sp, float4* __restrict__ dp) {
    __shared__ uint4 lb[8192];    // 128 KiB: whh frags | wth frags
    const int t = threadIdx.x, lane = t & 63, wave = t >> 6;
    const int l16 = lane & 15, quad = lane >> 4;
    const int isbf = (int)flag[0];

    {   // linear 128 KB stage: 1024 thr x 8 x 16B, once per block
        const uint4* s0 = (const uint4*)whh;
        const uint4* s1 = (const uint4*)wth;
        #pragma unroll
        for (int i = 0; i < 4; ++i) {
            lb[i * 1024 + t] = s0[i * 1024 + t];
            lb[4096 + i * 1024 + t] = s1[i * 1024 + t];
        }
    }
    __syncthreads();

    const int tile = (int)blockIdx.x * 16 + wave;
    if (tile >= NTILE) return;
    const int row = tile * 16 + l16;       // this lane's A row
    bf16x8 a[8];
    if (isbf) {
        const __bf16* xb = (const __bf16*)xe + (size_t)row * KEH;
        #pragma unroll
        for (int ks = 0; ks < 8; ++ks)
            a[ks] = *(const bf16x8*)(xb + ks * 32 + quad * 8);
    } else {
        const float* xf = (const float*)xe + (size_t)row * KEH;
        #pragma unroll
        for (int ks = 0; ks < 8; ++ks) {
            const float* p = xf + ks * 32 + quad * 8;
            float4 u0 = *(const float4*)p, u1 = *(const float4*)(p + 4);
            a[ks][0] = (__bf16)u0.x; a[ks][1] = (__bf16)u0.y;
            a[ks][2] = (__bf16)u0.z; a[ks][3] = (__bf16)u0.w;
            a[ks][4] = (__bf16)u1.x; a[ks][5] = (__bf16)u1.y;
            a[ks][6] = (__bf16)u1.z; a[ks][7] = (__bf16)u1.w;
        }
    }

    float hh0[4], hh1[4], ht0[4], ht1[4];  // phase-0 reduced scores
    float th0[4], th1[4], tt0[4], tt1[4];  // phase-1 reduced scores
    #pragma unroll
    for (int ph = 0; ph < 2; ++ph) {
        f32x4 acc[8];
        #pragma unroll
        for (int ct = 0; ct < 8; ++ct) acc[ct] = (f32x4){0.f, 0.f, 0.f, 0.f};
        #pragma unroll
        for (int ks = 0; ks < 8; ++ks)
            #pragma unroll
            for (int ct = 0; ct < 8; ++ct)
                acc[ct] = __builtin_amdgcn_mfma_f32_16x16x32_bf16(
                    a[ks], *(const bf16x8*)&lb[ph * 4096 + (ct * 8 + ks) * 64 + lane],
                    acc[ct], 0, 0, 0);

        // ---- epilogue: store projected rows + fused scores ----
        __hip_bfloat16* out = ph ? xt : xh;
        float s0[4] = {0.f,0.f,0.f,0.f}, s1[4] = {0.f,0.f,0.f,0.f};
        float s2[4] = {0.f,0.f,0.f,0.f}, s3[4] = {0.f,0.f,0.f,0.f};
        #pragma unroll
        for (int ct = 0; ct < 8; ++ct) {
            int c = ct * 16 + l16;
            float va0 = ah[c], va1 = ah[128 + c];
            float vb0 = at[c], vb1 = at[128 + c];
            #pragma unroll
            for (int jj = 0; jj < 4; ++jj) {
                float v = acc[ct][jj];
                s0[jj] = fmaf(v, va0, s0[jj]);
                s1[jj] = fmaf(v, va1, s1[jj]);
                s2[jj] = fmaf(v, vb0, s2[jj]);
                s3[jj] = fmaf(v, vb1, s3[jj]);
                out[(size_t)(tile * 16 + quad * 4 + jj) * KRH + c] = __float2bfloat16(v);
            }
        }
        #pragma unroll
        for (int off = 8; off; off >>= 1)
            #pragma unroll
            for (int jj = 0; jj < 4; ++jj) {
                s0[jj] += __shfl_xor(s0[jj], off);
                s1[jj] += __shfl_xor(s1[jj], off);
                s2[jj] += __shfl_xor(s2[jj], off);
                s3[jj] += __shfl_xor(s3[jj], off);
            }
        #pragma unroll
        for (int jj = 0; jj < 4; ++jj) {
            if (ph == 0) { hh0[jj] = s0[jj]; hh1[jj] = s1[jj]; ht0[jj] = s2[jj]; ht1[jj] = s3[jj]; }
            else         { th0[jj] = s0[jj]; th1[jj] = s1[jj]; tt0[jj] = s2[jj]; tt1[jj] = s3[jj]; }
        }
    }
    if (l16 == 0) {
        // sp = (s_hh0, s_hh1, s_th0, s_th1); dp = (s_tt0, s_tt1, s_ht0, s_ht1)
        #pragma unroll
        for (int jj = 0; jj < 4; ++jj) {
            int n = tile * 16 + quad * 4 + jj;
            sp[n] = make_float4(hh0[jj], hh1[jj], th0[jj], th1[jj]);
            dp[n] = make_float4(tt0[jj], tt1[jj], ht0[jj], ht1[jj]);
        }
    }
}

__device__ __forceinline__ float eexp(float x) {
    x = x > 0.f ? x : 0.01f * x;
    x = fminf(x, 50.f);
    return __expf(x);
}

// Per edge (contiguous 3125-edge range per block, 1024 thr = 16 waves/CU):
// 4 exp scores -> LDS segment sums + (rel,sbin) histograms -> global totals
// (atomic) AND this block's private hpb row (non-atomic). Per-block windows
// kept (round-9: global atomic cursors cost 7x write amplification).
__global__ __launch_bounds__(1024) void k_edge(const int* __restrict__ src, const int* __restrict__ dst,
                                               const int* __restrict__ rel,
                                               const float4* __restrict__ sp, const float4* __restrict__ dp,
                                               float* __restrict__ sums,
                                               unsigned* __restrict__ histH, unsigned* __restrict__ histT,
                                               unsigned* __restrict__ hpbH, unsigned* __restrict__ hpbT) {
    __shared__ float ls[NR * 4];
    __shared__ unsigned lhH[NBK], lhT[NBK];
    int t = threadIdx.x;
    for (int i = t; i < NR * 4; i += 1024) ls[i] = 0.f;
    for (int i = t; i < NBK; i += 1024) { lhH[i] = 0u; lhT[i] = 0u; }
    __syncthreads();
    unsigned lo = blockIdx.x * EPB, hi = lo + EPB;
    for (unsigned e = lo + t; e < hi; e += 1024) {
        int s = clampi(src[e], NN), d = clampi(dst[e], NN), r = clampi(rel[e], NR);
        float4 a = sp[s], b = dp[d];
        float4 ex;
        ex.x = eexp(a.x + b.x); ex.y = eexp(a.y + b.y);
        ex.z = eexp(a.z + b.z); ex.w = eexp(a.w + b.w);
        atomicAdd(&ls[r*4+0], ex.x);
        atomicAdd(&ls[r*4+1], ex.y);
        atomicAdd(&ls[r*4+2], ex.z);
        atomicAdd(&ls[r*4+3], ex.w);
        atomicAdd(&lhH[r * NSB + s / SBW], 1u);
        atomicAdd(&lhT[r * NSB + d / SBW], 1u);
    }
    __syncthreads();
    for (int i = t; i < NR * 4; i += 1024)
        if (ls[i] != 0.f) atomicAdd(&sums[i], ls[i]);
    size_t row = (size_t)blockIdx.x * NBK;
    for (int i = t; i < NBK; i += 1024) {
        unsigned cH = lhH[i], cT = lhT[i];
        hpbH[row + i] = cH;
        hpbT[row + i] = cT;
        if (cH) atomicAdd(&histH[i], cH);
        if (cT) atomicAdd(&histT[i], cT);
    }
}

// Fused scan (ordinary kernel — round-12 showed grid.sync costs ~300us).
// Grid 2*250 x 256 thr. Each block: (1) redundantly scans its pass's full
// 4000-bin hist into LDS bases (coalesced uint4 + wave shfl_up); (2)
// column-scans its 16-bin hpb slice (t=row, full 64B lines); slice-0
// blocks publish baseH/baseT(+NBK) and invs.
__global__ __launch_bounds__(256) void k_scan(const unsigned* __restrict__ histH,
                                              const unsigned* __restrict__ histT,
                                              const float* __restrict__ sums,
                                              unsigned* __restrict__ hpbH, unsigned* __restrict__ hpbT,
                                              unsigned* __restrict__ baseH, unsigned* __restrict__ baseT,
                                              float* __restrict__ invs) {
    __shared__ unsigned bases[4096];     // 16 KB (4000 used)
    __shared__ unsigned wsum[4];
    __shared__ unsigned wsum2[4][CSB];
    const int b = blockIdx.x;
    const int pass = b >= (NBK / CSB);
    const int slice = pass ? b - NBK / CSB : b;
    const unsigned* h = pass ? histT : histH;
    unsigned* hpb = pass ? hpbT : hpbH;
    unsigned* base = pass ? baseT : baseH;
    const int t = threadIdx.x, lane = t & 63, wv = t >> 6;

    // ---- (1) full hist scan -> bases ----
    {
        int j0 = t * 16;
        unsigned v[16], s = 0;
        const uint4* hp4 = (const uint4*)(h + j0);
        #pragma unroll
        for (int q = 0; q < 4; ++q) {
            uint4 u = (j0 + q * 4 < NBK) ? hp4[q] : make_uint4(0u, 0u, 0u, 0u);
            v[q*4+0] = u.x; v[q*4+1] = u.y; v[q*4+2] = u.z; v[q*4+3] = u.w;
        }
        #pragma unroll
        for (int k = 0; k < 16; ++k) {
            if (j0 + k >= NBK) v[k] = 0u;
            s += v[k];
        }
        unsigned inc = s;
        #pragma unroll
        for (int d = 1; d < 64; d <<= 1) {
            unsigned u = __shfl_up(inc, d);
            if (lane >= d) inc += u;
        }
        if (lane == 63) wsum[wv] = inc;
        __syncthreads();
        unsigned wbase = 0;
        for (int i = 0; i < wv; ++i) wbase += wsum[i];
        unsigned run = wbase + inc - s;
        #pragma unroll
        for (int k = 0; k < 16; ++k) {
            if (j0 + k < NBK) bases[j0 + k] = run;
            run += v[k];
        }
        __syncthreads();
        if (slice == 0) {
            for (int i = t; i < NBK; i += 256) base[i] = bases[i];
            if (t == 0) base[NBK] = wsum[0] + wsum[1] + wsum[2] + wsum[3];
        }
        if (b == 0) for (int i = t; i < NR * 4; i += 256) invs[i] = 1.f / (sums[i] + 1e-16f);
    }

    // ---- (2) colscan of this slice (t = hpb row) ----
    {
        int bin0 = slice * CSB;
        unsigned v[CSB], inc[CSB];
        uint4* hp = (uint4*)(hpb + (size_t)t * NBK + bin0);
        #pragma unroll
        for (int q = 0; q < CSB / 4; ++q) {
            uint4 u = hp[q];
            v[q*4+0] = u.x; v[q*4+1] = u.y; v[q*4+2] = u.z; v[q*4+3] = u.w;
        }
        #pragma unroll
        for (int k = 0; k < CSB; ++k) inc[k] = v[k];
        #pragma unroll
        for (int d = 1; d < 64; d <<= 1) {
            #pragma unroll
            for (int k = 0; k < CSB; ++k) {
                unsigned u = __shfl_up(inc[k], d);
                if (lane >= d) inc[k] += u;
            }
        }
        if (lane == 63) {
            #pragma unroll
            for (int k = 0; k < CSB; ++k) wsum2[wv][k] = inc[k];
        }
        __syncthreads();
        #pragma unroll
        for (int k = 0; k < CSB; ++k) {
            unsigned wbase = 0;
            for (int i = 0; i < wv; ++i) wbase += wsum2[i][k];
            v[k] = bases[bin0 + k] + wbase + inc[k] - v[k];
        }
        #pragma unroll
        for (int q = 0; q < CSB / 4; ++q)
            hp[q] = make_uint4(v[q*4+0], v[q*4+1], v[q*4+2], v[q*4+3]);
    }
}

// Single-pass scatter (1024 thr): recompute exp from L2-hot sp/dp; LDS
// cursors from precomputed per-block offsets.
__global__ __launch_bounds__(1024) void k_mkrec(const int* __restrict__ src, const int* __restrict__ dst,
                                                const int* __restrict__ rel,
                                                const float4* __restrict__ sp, const float4* __restrict__ dp,
                                                const float4* __restrict__ invs4,
                                                const unsigned* __restrict__ hpbH, const unsigned* __restrict__ hpbT,
                                                uint2* __restrict__ recH, uint2* __restrict__ recT) {
    __shared__ unsigned lcH[NBK], lcT[NBK];
    int t = threadIdx.x;
    size_t row = (size_t)blockIdx.x * NBK;
    for (int i = t; i < NBK; i += 1024) { lcH[i] = hpbH[row + i]; lcT[i] = hpbT[row + i]; }
    __syncthreads();
    unsigned lo = blockIdx.x * EPB, hi = lo + EPB;
    for (unsigned e = lo + t; e < hi; e += 1024) {
        int s = clampi(src[e], NN), d = clampi(dst[e], NN), r = clampi(rel[e], NR);
        float4 a = sp[s], b = dp[d];
        float4 iv = invs4[r];
        float exx = eexp(a.x + b.x), exy = eexp(a.y + b.y);
        float exz = eexp(a.z + b.z), exw = eexp(a.w + b.w);
        float w1 = exx * iv.x + exy * iv.y;
        float w2 = exz * iv.z + exw * iv.w;
        unsigned pH = atomicAdd(&lcH[r * NSB + s / SBW], 1u);
        unsigned pT = atomicAdd(&lcT[r * NSB + d / SBW], 1u);
        if (pH < NE) recH[pH] = make_uint2((unsigned)s, __float_as_uint(w1));
        if (pT < NE) recT[pT] = make_uint2((unsigned)d, __float_as_uint(w2));
    }
}

// One block per (rel,sbin) bucket. Chunked rec staging (256/LDS burst), then
// 16-lane-group gather, 4 records deep: 4 independent b128 gathers issued
// before the FMA block hide gather latency. Group reduce: shfl_xor(16,32)
// then LDS cross-wave sum.
__global__ __launch_bounds__(256) void k_accR(const uint2* __restrict__ recH, const uint2* __restrict__ recT,
                                              const unsigned* __restrict__ baseH, const unsigned* __restrict__ baseT,
                                              const __hip_bfloat16* __restrict__ xh,
                                              const __hip_bfloat16* __restrict__ xt,
                                              float* __restrict__ part) {
    __shared__ float red[3][128];
    __shared__ uint2 lrec[256];
    int b = blockIdx.x;
    int t = threadIdx.x, lane = t & 63, wv = t >> 6;
    int l16 = lane & 15, g = lane >> 4;      // col sub-slice, record subgroup
    float az[8];
    #pragma unroll
    for (int k = 0; k < 8; ++k) az[k] = 0.f;

    for (int pass = 0; pass < 2; ++pass) {
        const uint2* rec = pass ? recT : recH;
        const unsigned* base = pass ? baseT : baseH;
        const uint4* xs = (const uint4*)(pass ? xt : xh);   // row = 16 uint4
        unsigned b0 = base[b];
        unsigned cnt = base[b + 1] - b0;
        if (cnt > NE) cnt = 0;        // poison guard
        for (unsigned cb = 0; cb < cnt; cb += 256u) {
            unsigned cn = cnt - cb; if (cn > 256u) cn = 256u;
            __syncthreads();                       // prior chunk readers done
            if ((unsigned)t < cn) lrec[t] = rec[b0 + cb + t];
            __syncthreads();
            unsigned j = (unsigned)(wv * 4 + g);
            // 4-deep main loop: records j, j+16, j+32, j+48
            for (; j + 48u < cn; j += 64u) {
                uint2 v0 = lrec[j], v1 = lrec[j + 16u], v2 = lrec[j + 32u], v3 = lrec[j + 48u];
                unsigned n0 = v0.x < NN ? v0.x : 0u;
                unsigned n1 = v1.x < NN ? v1.x : 0u;
                unsigned n2 = v2.x < NN ? v2.x : 0u;
                unsigned n3 = v3.x < NN ? v3.x : 0u;
                uint4 u0 = xs[(size_t)n0 * 16 + l16];
                uint4 u1 = xs[(size_t)n1 * 16 + l16];
                uint4 u2 = xs[(size_t)n2 * 16 + l16];
                uint4 u3 = xs[(size_t)n3 * 16 + l16];
                float w0 = __uint_as_float(v0.y), w1 = __uint_as_float(v1.y);
                float w2 = __uint_as_float(v2.y), w3 = __uint_as_float(v3.y);
                az[0] = fmaf(w0, __uint_as_float(u0.x << 16),         az[0]);
                az[1] = fmaf(w0, __uint_as_float(u0.x & 0xffff0000u), az[1]);
                az[2] = fmaf(w0, __uint_as_float(u0.y << 16),         az[2]);
                az[3] = fmaf(w0, __uint_as_float(u0.y & 0xffff0000u), az[3]);
                az[4] = fmaf(w0, __uint_as_float(u0.z << 16),         az[4]);
                az[5] = fmaf(w0, __uint_as_float(u0.z & 0xffff0000u), az[5]);
                az[6] = fmaf(w0, __uint_as_float(u0.w << 16),         az[6]);
                az[7] = fmaf(w0, __uint_as_float(u0.w & 0xffff0000u), az[7]);
                az[0] = fmaf(w1, __uint_as_float(u1.x << 16),         az[0]);
                az[1] = fmaf(w1, __uint_as_float(u1.x & 0xffff0000u), az[1]);
                az[2] = fmaf(w1, __uint_as_float(u1.y << 16),         az[2]);
                az[3] = fmaf(w1, __uint_as_float(u1.y & 0xffff0000u), az[3]);
                az[4] = fmaf(w1, __uint_as_float(u1.z << 16),         az[4]);
                az[5] = fmaf(w1, __uint_as_float(u1.z & 0xffff0000u), az[5]);
                az[6] = fmaf(w1, __uint_as_float(u1.w << 16),         az[6]);
                az[7] = fmaf(w1, __uint_as_float(u1.w & 0xffff0000u), az[7]);
                az[0] = fmaf(w2, __uint_as_float(u2.x << 16),         az[0]);
                az[1] = fmaf(w2, __uint_as_float(u2.x & 0xffff0000u), az[1]);
                az[2] = fmaf(w2, __uint_as_float(u2.y << 16),         az[2]);
                az[3] = fmaf(w2, __uint_as_float(u2.y & 0xffff0000u), az[3]);
                az[4] = fmaf(w2, __uint_as_float(u2.z << 16),         az[4]);
                az[5] = fmaf(w2, __uint_as_float(u2.z & 0xffff0000u), az[5]);
                az[6] = fmaf(w2, __uint_as_float(u2.w << 16),         az[6]);
                az[7] = fmaf(w2, __uint_as_float(u2.w & 0xffff0000u), az[7]);
                az[0] = fmaf(w3, __uint_as_float(u3.x << 16),         az[0]);
                az[1] = fmaf(w3, __uint_as_float(u3.x & 0xffff0000u), az[1]);
                az[2] = fmaf(w3, __uint_as_float(u3.y << 16),         az[2]);
                az[3] = fmaf(w3, __uint_as_float(u3.y & 0xffff0000u), az[3]);
                az[4] = fmaf(w3, __uint_as_float(u3.z << 16),         az[4]);
                az[5] = fmaf(w3, __uint_as_float(u3.z & 0xffff0000u), az[5]);
                az[6] = fmaf(w3, __uint_as_float(u3.w << 16),         az[6]);
                az[7] = fmaf(w3, __uint_as_float(u3.w & 0xffff0000u), az[7]);
            }
            // tail
            for (; j < cn; j += 16u) {
                uint2 v = lrec[j];
                unsigned nd = v.x < NN ? v.x : 0u;
                float w = __uint_as_float(v.y);
                uint4 u = xs[(size_t)nd * 16 + l16];
                az[0] = fmaf(w, __uint_as_float(u.x << 16),          az[0]);
                az[1] = fmaf(w, __uint_as_float(u.x & 0xffff0000u),  az[1]);
                az[2] = fmaf(w, __uint_as_float(u.y << 16),          az[2]);
                az[3] = fmaf(w, __uint_as_float(u.y & 0xffff0000u),  az[3]);
                az[4] = fmaf(w, __uint_as_float(u.z << 16),          az[4]);
                az[5] = fmaf(w, __uint_as_float(u.z & 0xffff0000u),  az[5]);
                az[6] = fmaf(w, __uint_as_float(u.w << 16),          az[6]);
                az[7] = fmaf(w, __uint_as_float(u.w & 0xffff0000u),  az[7]);
            }
        }
    }
    // reduce the 4 record-subgroups: lanes 0-15 end with column totals
    #pragma unroll
    for (int k = 0; k < 8; ++k) {
        az[k] += __shfl_xor(az[k], 16);
        az[k] += __shfl_xor(az[k], 32);
    }
    __syncthreads();                  // lrec dead; red reuse safe
    if (wv > 0 && lane < 16) {
        #pragma unroll
        for (int k = 0; k < 8; ++k) red[wv - 1][l16 * 8 + k] = az[k];
    }
    __syncthreads();
    if (wv == 0 && lane < 16) {
        #pragma unroll
        for (int k = 0; k < 8; ++k) {
            float s = az[k] + red[0][l16 * 8 + k] + red[1][l16 * 8 + k] + red[2][l16 * 8 + k];
            part[(size_t)b * KRH + l16 * 8 + k] = s;
        }
    }
}

// out[r][c] = 0.25 * sum_sbin part[r*8+sbin][c]; dtype follows input.
__global__ __launch_bounds__(256) void k_out(const float* __restrict__ part,
                                             const unsigned* __restrict__ flag, void* __restrict__ out) {
    int i = blockIdx.x * 256 + threadIdx.x;
    if (i < NR * KRH) {
        int r = i >> 7, c = i & 127;
        float v = 0.f;
        for (int s = 0; s < NSB; ++s) v += part[(size_t)(r * NSB + s) * KRH + c];
        v *= 0.25f;                   // / num_heads(2) / 2
        if (!isfinite(v)) v = 0.f;
        if (flag[0]) ((__hip_bfloat16*)out)[i] = __float2bfloat16(v);
        else         ((float*)out)[i] = v;
    }
}

extern "C" void kernel_launch(void* const* d_in, const int* in_sizes, int n_in,
                              void* d_out, int out_size, void* d_ws, size_t ws_size,
                              hipStream_t stream) {
    const void* xe  = d_in[0];
    const int* eidx = (const int*)d_in[1];
    const int* rel  = (const int*)d_in[2];
    const void* wh  = d_in[3];
    const void* wt  = d_in[4];
    const void* ahp = d_in[5];
    const void* atp = d_in[6];

    const int* src = eidx;
    const int* dst = eidx + NE;

    char* ws = (char*)d_ws;
    __hip_bfloat16* xh = (__hip_bfloat16*)(ws + OFF_XH);
    __hip_bfloat16* xt = (__hip_bfloat16*)(ws + OFF_XT);
    float4*   sp     = (float4*)(ws + OFF_SP);
    float4*   dp     = (float4*)(ws + OFF_DP);
    float*    sums   = (float*)(ws + OFF_SUMS);
    unsigned* histH  = (unsigned*)(ws + OFF_HISTH);
    unsigned* histT  = (unsigned*)(ws + OFF_HISTT);
    float*    invs   = (float*)(ws + OFF_INVS);
    unsigned* baseH  = (unsigned*)(ws + OFF_BASEH);
    unsigned* baseT  = (unsigned*)(ws + OFF_BASET);
    uint2*    recH   = (uint2*)(ws + OFF_RECH);
    uint2*    recT   = (uint2*)(ws + OFF_RECT);
    float*    partp  = (float*)(ws + OFF_PART);
    float*    ah32   = (float*)(ws + OFF_AH);
    float*    at32   = (float*)(ws + OFF_AT);
    unsigned* flag   = (unsigned*)(ws + OFF_FLAG);
    __bf16*   whh    = (__bf16*)(ws + OFF_WHH);
    __bf16*   wth    = (__bf16*)(ws + OFF_WTH);
    unsigned* hpbH   = (unsigned*)(ws + OFF_HPBH);
    unsigned* hpbT   = (unsigned*)(ws + OFF_HPBT);

    k_init<<<161, 256, 0, stream>>>((const unsigned*)xe, ahp, atp, wh, wt, flag, ah32, at32,
                                     whh, wth, (unsigned*)(ws + OFF_SUMS));
    k_gemm<<<(NTILE + 15) / 16, 1024, 0, stream>>>(xe, flag, whh, wth, ah32, at32, xh, xt, sp, dp);
    k_edge<<<NBE, 1024, 0, stream>>>(src, dst, rel, sp, dp, sums, histH, histT, hpbH, hpbT);
    k_scan<<<2 * (NBK / CSB), 256, 0, stream>>>(histH, histT, sums, hpbH, hpbT, baseH, baseT, invs);
    k_mkrec<<<NBE, 1024, 0, stream>>>(src, dst, rel, sp, dp, (const float4*)invs, hpbH, hpbT, recH, recT);
    k_accR<<<NBK, 256, 0, stream>>>(recH, recT, baseH, baseT, xh, xt, partp);
    k_out<<<(NR * KRH + 255) / 256, 256, 0, stream>>>(partp, flag, d_out);
}

// Round 16
// 219.227 us; speedup vs baseline: 1.0195x; 1.0195x over previous
//
#include <hip/hip_runtime.h>
#include <hip/hip_bf16.h>

#define NN 50000      // nodes
#define NE 800000     // edges
#define NR 500        // relations
#define KEH 256       // input feat dim
#define KRH 128       // proj feat dim
#define NSB 8         // node super-bins (node / 6250), aligned to 8 XCDs
#define SBW 6250      // super-bin width
#define NBK (NR*NSB)  // 4000 buckets
#define NBE 256       // edge-pass blocks (k_edge / k_mkrec)
#define EPB (NE/NBE)  // 3125 edges per block
#define NTILE 3125    // 16-row GEMM tiles (50000/16 exactly)
#define CSB 16        // k_scan bins per slice (NBK/CSB = 250 slices/pass)

typedef __attribute__((ext_vector_type(8))) __bf16 bf16x8;
typedef __attribute__((ext_vector_type(4))) float f32x4;

// ---- workspace layout (bytes, 16B aligned), total ~50.6 MiB ----
#define OFF_XH     0UL            // [NN][128] bf16
#define OFF_XT     12800000UL     // [NN][128] bf16
#define OFF_SP     25600000UL     // [NN] float4
#define OFF_DP     26400000UL     // [NN] float4
#define OFF_SUMS   27200000UL     // [NR*4] f32 (8000 B)
#define OFF_HISTH  27208000UL     // [NBK] u32 totals (16000 B)
#define OFF_HISTT  27224000UL     // [NBK] u32 totals (16000 B)
// zero region SUMS..HISTT = 40000 B = 10000 u32
#define OFF_INVS   27240000UL     // [NR*4] f32
#define OFF_BASEH  27248000UL     // [NBK+1] u32 (16016 B)
#define OFF_BASET  27264016UL     // [NBK+1] u32
#define OFF_RECH   27312032UL     // [NE] uint2 (node, w1) 6.4 MB
#define OFF_RECT   33712032UL     // [NE] uint2 (node, w2) 6.4 MB
#define OFF_PART   40112032UL     // [NBK][128] f32 partials (2.048 MB)
#define OFF_AH     42160032UL     // [256] f32
#define OFF_AT     42161056UL     // [256] f32
#define OFF_FLAG   42162080UL     // u32
#define OFF_WHH    42162144UL     // [128][256] bf16, FRAGMENT order
#define OFF_WTH    42293216UL
#define OFF_HPBH   42424288UL     // [NBE][NBK] u32 per-block hist/offsets 4.096 MB
#define OFF_HPBT   46520288UL     // [NBE][NBK] u32                       4.096 MB
// end 50,616,288

__device__ __forceinline__ int clampi(int v, int hi) {  // [0, hi)
    v = v < 0 ? 0 : v;
    return v >= hi ? hi - 1 : v;
}

// Wave-replicated dtype sniff (see round-8 notes).
__device__ __forceinline__ int sniff_isbf(const unsigned* xe_raw) {
    int lane = threadIdx.x & 63;
    unsigned w = xe_raw[lane];
    unsigned ex = (w >> 7) & 0xFFu;
    bool hit = (ex >= 115u && ex <= 131u);
    return __popcll(__ballot(hit)) >= 32;
}

// block 0: flag + a_h/a_t convert. blocks 1..128: weight -> FRAGMENT order
// (bf16 cast). blocks 129+: zero sums + histH + histT (10000 u32).
// Frag order: out index o = ((ct*8+ks)*64 + q*16 + c)*8 + e  holds
// w[ct*16+c][ks*32+q*8+e]  — lane l=q*16+c of fragment (ct,ks) reads its
// 8 contiguous bf16 (col=l&15, k-seg=(l>>4)*8) as one 16B chunk; the LDS
// stage is a linear 64KB copy.
__global__ __launch_bounds__(256) void k_init(const unsigned* __restrict__ xe_raw,
                                              const void* __restrict__ ah_in, const void* __restrict__ at_in,
                                              const void* __restrict__ wh, const void* __restrict__ wt,
                                              unsigned* __restrict__ flag, float* __restrict__ ah32,
                                              float* __restrict__ at32,
                                              __bf16* __restrict__ whh, __bf16* __restrict__ wth,
                                              unsigned* __restrict__ zero1) {
    int isbf = sniff_isbf(xe_raw);
    int t = threadIdx.x;
    if (blockIdx.x == 0) {
        if (t == 0) flag[0] = (unsigned)isbf;
        ah32[t] = isbf ? __bfloat162float(((const __hip_bfloat16*)ah_in)[t]) : ((const float*)ah_in)[t];
        at32[t] = isbf ? __bfloat162float(((const __hip_bfloat16*)at_in)[t]) : ((const float*)at_in)[t];
    } else if (blockIdx.x <= 128) {
        int o = (blockIdx.x - 1) * 256 + t;   // [0, 32768) frag-order output idx
        int e = o & 7, c = (o >> 3) & 15, q = (o >> 7) & 3, ks = (o >> 9) & 7, ct = o >> 12;
        int i = (ct * 16 + c) * KEH + ks * 32 + q * 8 + e;   // row-major source
        if (isbf) {
            whh[o] = ((const __bf16*)wh)[i];
            wth[o] = ((const __bf16*)wt)[i];
        } else {
            whh[o] = (__bf16)((const float*)wh)[i];
            wth[o] = (__bf16)((const float*)wt)[i];
        }
    } else {
        int stride = (gridDim.x - 129) * 256;
        for (int i = (blockIdx.x - 129) * 256 + t; i < 10000; i += stride) zero1[i] = 0u;
    }
}

// One-pass both-phase GEMM + fused per-node scores, single-term bf16 MFMA.
// Round-16: grid 256 (ALL CUs — round-15's grid of 196 left 60 CUs idle,
// cancelling the 16-wave occupancy gain) x 1024 thr (16 waves = 4/SIMD).
// Wave->tile map: tile = wave*256 + bid — every block gets 12-13 active
// waves, work even across CUs. Both fragment-order weight matrices staged
// into LDS once per block (128 KB -> 1 block/CU); xe read ONCE (both
// phases per tile). VGPR 112 fits the 128-cap of launch_bounds(1024,4).
__global__ __launch_bounds__(1024, 4) void k_gemm(const void* __restrict__ xe,
                                              const unsigned* __restrict__ flag,
                                              const __bf16* __restrict__ whh, const __bf16* __restrict__ wth,
                                              const float* __restrict__ ah, const float* __restrict__ at,
                                              __hip_bfloat16* __restrict__ xh, __hip_bfloat16* __restrict__ xt,
                                              float4* __restrict__ sp, float4* __restrict__ dp) {
    __shared__ uint4 lb[8192];    // 128 KiB: whh frags | wth frags
    const int t = threadIdx.x, lane = t & 63, wave = t >> 6;
    const int l16 = lane & 15, quad = lane >> 4;
    const int isbf = (int)flag[0];

    {   // linear 128 KB stage: 1024 thr x 8 x 16B, once per block
        const uint4* s0 = (const uint4*)whh;
        const uint4* s1 = (const uint4*)wth;
        #pragma unroll
        for (int i = 0; i < 4; ++i) {
            lb[i * 1024 + t] = s0[i * 1024 + t];
            lb[4096 + i * 1024 + t] = s1[i * 1024 + t];
        }
    }
    __syncthreads();

    const int tile = wave * 256 + (int)blockIdx.x;   // even spread over 256 CUs
    if (tile >= NTILE) return;
    const int row = tile * 16 + l16;       // this lane's A row
    bf16x8 a[8];
    if (isbf) {
        const __bf16* xb = (const __bf16*)xe + (size_t)row * KEH;
        #pragma unroll
        for (int ks = 0; ks < 8; ++ks)
            a[ks] = *(const bf16x8*)(xb + ks * 32 + quad * 8);
    } else {
        const float* xf = (const float*)xe + (size_t)row * KEH;
        #pragma unroll
        for (int ks = 0; ks < 8; ++ks) {
            const float* p = xf + ks * 32 + quad * 8;
            float4 u0 = *(const float4*)p, u1 = *(const float4*)(p + 4);
            a[ks][0] = (__bf16)u0.x; a[ks][1] = (__bf16)u0.y;
            a[ks][2] = (__bf16)u0.z; a[ks][3] = (__bf16)u0.w;
            a[ks][4] = (__bf16)u1.x; a[ks][5] = (__bf16)u1.y;
            a[ks][6] = (__bf16)u1.z; a[ks][7] = (__bf16)u1.w;
        }
    }

    float hh0[4], hh1[4], ht0[4], ht1[4];  // phase-0 reduced scores
    float th0[4], th1[4], tt0[4], tt1[4];  // phase-1 reduced scores
    #pragma unroll
    for (int ph = 0; ph < 2; ++ph) {
        f32x4 acc[8];
        #pragma unroll
        for (int ct = 0; ct < 8; ++ct) acc[ct] = (f32x4){0.f, 0.f, 0.f, 0.f};
        #pragma unroll
        for (int ks = 0; ks < 8; ++ks)
            #pragma unroll
            for (int ct = 0; ct < 8; ++ct)
                acc[ct] = __builtin_amdgcn_mfma_f32_16x16x32_bf16(
                    a[ks], *(const bf16x8*)&lb[ph * 4096 + (ct * 8 + ks) * 64 + lane],
                    acc[ct], 0, 0, 0);

        // ---- epilogue: store projected rows + fused scores ----
        __hip_bfloat16* out = ph ? xt : xh;
        float s0[4] = {0.f,0.f,0.f,0.f}, s1[4] = {0.f,0.f,0.f,0.f};
        float s2[4] = {0.f,0.f,0.f,0.f}, s3[4] = {0.f,0.f,0.f,0.f};
        #pragma unroll
        for (int ct = 0; ct < 8; ++ct) {
            int c = ct * 16 + l16;
            float va0 = ah[c], va1 = ah[128 + c];
            float vb0 = at[c], vb1 = at[128 + c];
            #pragma unroll
            for (int jj = 0; jj < 4; ++jj) {
                float v = acc[ct][jj];
                s0[jj] = fmaf(v, va0, s0[jj]);
                s1[jj] = fmaf(v, va1, s1[jj]);
                s2[jj] = fmaf(v, vb0, s2[jj]);
                s3[jj] = fmaf(v, vb1, s3[jj]);
                out[(size_t)(tile * 16 + quad * 4 + jj) * KRH + c] = __float2bfloat16(v);
            }
        }
        #pragma unroll
        for (int off = 8; off; off >>= 1)
            #pragma unroll
            for (int jj = 0; jj < 4; ++jj) {
                s0[jj] += __shfl_xor(s0[jj], off);
                s1[jj] += __shfl_xor(s1[jj], off);
                s2[jj] += __shfl_xor(s2[jj], off);
                s3[jj] += __shfl_xor(s3[jj], off);
            }
        #pragma unroll
        for (int jj = 0; jj < 4; ++jj) {
            if (ph == 0) { hh0[jj] = s0[jj]; hh1[jj] = s1[jj]; ht0[jj] = s2[jj]; ht1[jj] = s3[jj]; }
            else         { th0[jj] = s0[jj]; th1[jj] = s1[jj]; tt0[jj] = s2[jj]; tt1[jj] = s3[jj]; }
        }
    }
    if (l16 == 0) {
        // sp = (s_hh0, s_hh1, s_th0, s_th1); dp = (s_tt0, s_tt1, s_ht0, s_ht1)
        #pragma unroll
        for (int jj = 0; jj < 4; ++jj) {
            int n = tile * 16 + quad * 4 + jj;
            sp[n] = make_float4(hh0[jj], hh1[jj], th0[jj], th1[jj]);
            dp[n] = make_float4(tt0[jj], tt1[jj], ht0[jj], ht1[jj]);
        }
    }
}

__device__ __forceinline__ float eexp(float x) {
    x = x > 0.f ? x : 0.01f * x;
    x = fminf(x, 50.f);
    return __expf(x);
}

// Per edge (contiguous 3125-edge range per block, 1024 thr = 16 waves/CU):
// 4 exp scores -> LDS segment sums + (rel,sbin) histograms -> global totals
// (atomic) AND this block's private hpb row (non-atomic). Per-block windows
// kept (round-9: global atomic cursors cost 7x write amplification).
__global__ __launch_bounds__(1024) void k_edge(const int* __restrict__ src, const int* __restrict__ dst,
                                               const int* __restrict__ rel,
                                               const float4* __restrict__ sp, const float4* __restrict__ dp,
                                               float* __restrict__ sums,
                                               unsigned* __restrict__ histH, unsigned* __restrict__ histT,
                                               unsigned* __restrict__ hpbH, unsigned* __restrict__ hpbT) {
    __shared__ float ls[NR * 4];
    __shared__ unsigned lhH[NBK], lhT[NBK];
    int t = threadIdx.x;
    for (int i = t; i < NR * 4; i += 1024) ls[i] = 0.f;
    for (int i = t; i < NBK; i += 1024) { lhH[i] = 0u; lhT[i] = 0u; }
    __syncthreads();
    unsigned lo = blockIdx.x * EPB, hi = lo + EPB;
    for (unsigned e = lo + t; e < hi; e += 1024) {
        int s = clampi(src[e], NN), d = clampi(dst[e], NN), r = clampi(rel[e], NR);
        float4 a = sp[s], b = dp[d];
        float4 ex;
        ex.x = eexp(a.x + b.x); ex.y = eexp(a.y + b.y);
        ex.z = eexp(a.z + b.z); ex.w = eexp(a.w + b.w);
        atomicAdd(&ls[r*4+0], ex.x);
        atomicAdd(&ls[r*4+1], ex.y);
        atomicAdd(&ls[r*4+2], ex.z);
        atomicAdd(&ls[r*4+3], ex.w);
        atomicAdd(&lhH[r * NSB + s / SBW], 1u);
        atomicAdd(&lhT[r * NSB + d / SBW], 1u);
    }
    __syncthreads();
    for (int i = t; i < NR * 4; i += 1024)
        if (ls[i] != 0.f) atomicAdd(&sums[i], ls[i]);
    size_t row = (size_t)blockIdx.x * NBK;
    for (int i = t; i < NBK; i += 1024) {
        unsigned cH = lhH[i], cT = lhT[i];
        hpbH[row + i] = cH;
        hpbT[row + i] = cT;
        if (cH) atomicAdd(&histH[i], cH);
        if (cT) atomicAdd(&histT[i], cT);
    }
}

// Fused scan (ordinary kernel — round-12 showed grid.sync costs ~300us).
// Grid 2*250 x 256 thr. Each block: (1) redundantly scans its pass's full
// 4000-bin hist into LDS bases (coalesced uint4 + wave shfl_up); (2)
// column-scans its 16-bin hpb slice (t=row, full 64B lines); slice-0
// blocks publish baseH/baseT(+NBK) and invs.
__global__ __launch_bounds__(256) void k_scan(const unsigned* __restrict__ histH,
                                              const unsigned* __restrict__ histT,
                                              const float* __restrict__ sums,
                                              unsigned* __restrict__ hpbH, unsigned* __restrict__ hpbT,
                                              unsigned* __restrict__ baseH, unsigned* __restrict__ baseT,
                                              float* __restrict__ invs) {
    __shared__ unsigned bases[4096];     // 16 KB (4000 used)
    __shared__ unsigned wsum[4];
    __shared__ unsigned wsum2[4][CSB];
    const int b = blockIdx.x;
    const int pass = b >= (NBK / CSB);
    const int slice = pass ? b - NBK / CSB : b;
    const unsigned* h = pass ? histT : histH;
    unsigned* hpb = pass ? hpbT : hpbH;
    unsigned* base = pass ? baseT : baseH;
    const int t = threadIdx.x, lane = t & 63, wv = t >> 6;

    // ---- (1) full hist scan -> bases ----
    {
        int j0 = t * 16;
        unsigned v[16], s = 0;
        const uint4* hp4 = (const uint4*)(h + j0);
        #pragma unroll
        for (int q = 0; q < 4; ++q) {
            uint4 u = (j0 + q * 4 < NBK) ? hp4[q] : make_uint4(0u, 0u, 0u, 0u);
            v[q*4+0] = u.x; v[q*4+1] = u.y; v[q*4+2] = u.z; v[q*4+3] = u.w;
        }
        #pragma unroll
        for (int k = 0; k < 16; ++k) {
            if (j0 + k >= NBK) v[k] = 0u;
            s += v[k];
        }
        unsigned inc = s;
        #pragma unroll
        for (int d = 1; d < 64; d <<= 1) {
            unsigned u = __shfl_up(inc, d);
            if (lane >= d) inc += u;
        }
        if (lane == 63) wsum[wv] = inc;
        __syncthreads();
        unsigned wbase = 0;
        for (int i = 0; i < wv; ++i) wbase += wsum[i];
        unsigned run = wbase + inc - s;
        #pragma unroll
        for (int k = 0; k < 16; ++k) {
            if (j0 + k < NBK) bases[j0 + k] = run;
            run += v[k];
        }
        __syncthreads();
        if (slice == 0) {
            for (int i = t; i < NBK; i += 256) base[i] = bases[i];
            if (t == 0) base[NBK] = wsum[0] + wsum[1] + wsum[2] + wsum[3];
        }
        if (b == 0) for (int i = t; i < NR * 4; i += 256) invs[i] = 1.f / (sums[i] + 1e-16f);
    }

    // ---- (2) colscan of this slice (t = hpb row) ----
    {
        int bin0 = slice * CSB;
        unsigned v[CSB], inc[CSB];
        uint4* hp = (uint4*)(hpb + (size_t)t * NBK + bin0);
        #pragma unroll
        for (int q = 0; q < CSB / 4; ++q) {
            uint4 u = hp[q];
            v[q*4+0] = u.x; v[q*4+1] = u.y; v[q*4+2] = u.z; v[q*4+3] = u.w;
        }
        #pragma unroll
        for (int k = 0; k < CSB; ++k) inc[k] = v[k];
        #pragma unroll
        for (int d = 1; d < 64; d <<= 1) {
            #pragma unroll
            for (int k = 0; k < CSB; ++k) {
                unsigned u = __shfl_up(inc[k], d);
                if (lane >= d) inc[k] += u;
            }
        }
        if (lane == 63) {
            #pragma unroll
            for (int k = 0; k < CSB; ++k) wsum2[wv][k] = inc[k];
        }
        __syncthreads();
        #pragma unroll
        for (int k = 0; k < CSB; ++k) {
            unsigned wbase = 0;
            for (int i = 0; i < wv; ++i) wbase += wsum2[i][k];
            v[k] = bases[bin0 + k] + wbase + inc[k] - v[k];
        }
        #pragma unroll
        for (int q = 0; q < CSB / 4; ++q)
            hp[q] = make_uint4(v[q*4+0], v[q*4+1], v[q*4+2], v[q*4+3]);
    }
}

// Single-pass scatter (1024 thr): recompute exp from L2-hot sp/dp; LDS
// cursors from precomputed per-block offsets.
__global__ __launch_bounds__(1024) void k_mkrec(const int* __restrict__ src, const int* __restrict__ dst,
                                                const int* __restrict__ rel,
                                                const float4* __restrict__ sp, const float4* __restrict__ dp,
                                                const float4* __restrict__ invs4,
                                                const unsigned* __restrict__ hpbH, const unsigned* __restrict__ hpbT,
                                                uint2* __restrict__ recH, uint2* __restrict__ recT) {
    __shared__ unsigned lcH[NBK], lcT[NBK];
    int t = threadIdx.x;
    size_t row = (size_t)blockIdx.x * NBK;
    for (int i = t; i < NBK; i += 1024) { lcH[i] = hpbH[row + i]; lcT[i] = hpbT[row + i]; }
    __syncthreads();
    unsigned lo = blockIdx.x * EPB, hi = lo + EPB;
    for (unsigned e = lo + t; e < hi; e += 1024) {
        int s = clampi(src[e], NN), d = clampi(dst[e], NN), r = clampi(rel[e], NR);
        float4 a = sp[s], b = dp[d];
        float4 iv = invs4[r];
        float exx = eexp(a.x + b.x), exy = eexp(a.y + b.y);
        float exz = eexp(a.z + b.z), exw = eexp(a.w + b.w);
        float w1 = exx * iv.x + exy * iv.y;
        float w2 = exz * iv.z + exw * iv.w;
        unsigned pH = atomicAdd(&lcH[r * NSB + s / SBW], 1u);
        unsigned pT = atomicAdd(&lcT[r * NSB + d / SBW], 1u);
        if (pH < NE) recH[pH] = make_uint2((unsigned)s, __float_as_uint(w1));
        if (pT < NE) recT[pT] = make_uint2((unsigned)d, __float_as_uint(w2));
    }
}

// One block per (rel,sbin) bucket. Chunked rec staging (256/LDS burst), then
// 16-lane-group gather, 4 records deep: 4 independent b128 gathers issued
// before the FMA block hide gather latency. Group reduce: shfl_xor(16,32)
// then LDS cross-wave sum.
__global__ __launch_bounds__(256) void k_accR(const uint2* __restrict__ recH, const uint2* __restrict__ recT,
                                              const unsigned* __restrict__ baseH, const unsigned* __restrict__ baseT,
                                              const __hip_bfloat16* __restrict__ xh,
                                              const __hip_bfloat16* __restrict__ xt,
                                              float* __restrict__ part) {
    __shared__ float red[3][128];
    __shared__ uint2 lrec[256];
    int b = blockIdx.x;
    int t = threadIdx.x, lane = t & 63, wv = t >> 6;
    int l16 = lane & 15, g = lane >> 4;      // col sub-slice, record subgroup
    float az[8];
    #pragma unroll
    for (int k = 0; k < 8; ++k) az[k] = 0.f;

    for (int pass = 0; pass < 2; ++pass) {
        const uint2* rec = pass ? recT : recH;
        const unsigned* base = pass ? baseT : baseH;
        const uint4* xs = (const uint4*)(pass ? xt : xh);   // row = 16 uint4
        unsigned b0 = base[b];
        unsigned cnt = base[b + 1] - b0;
        if (cnt > NE) cnt = 0;        // poison guard
        for (unsigned cb = 0; cb < cnt; cb += 256u) {
            unsigned cn = cnt - cb; if (cn > 256u) cn = 256u;
            __syncthreads();                       // prior chunk readers done
            if ((unsigned)t < cn) lrec[t] = rec[b0 + cb + t];
            __syncthreads();
            unsigned j = (unsigned)(wv * 4 + g);
            // 4-deep main loop: records j, j+16, j+32, j+48
            for (; j + 48u < cn; j += 64u) {
                uint2 v0 = lrec[j], v1 = lrec[j + 16u], v2 = lrec[j + 32u], v3 = lrec[j + 48u];
                unsigned n0 = v0.x < NN ? v0.x : 0u;
                unsigned n1 = v1.x < NN ? v1.x : 0u;
                unsigned n2 = v2.x < NN ? v2.x : 0u;
                unsigned n3 = v3.x < NN ? v3.x : 0u;
                uint4 u0 = xs[(size_t)n0 * 16 + l16];
                uint4 u1 = xs[(size_t)n1 * 16 + l16];
                uint4 u2 = xs[(size_t)n2 * 16 + l16];
                uint4 u3 = xs[(size_t)n3 * 16 + l16];
                float w0 = __uint_as_float(v0.y), w1 = __uint_as_float(v1.y);
                float w2 = __uint_as_float(v2.y), w3 = __uint_as_float(v3.y);
                az[0] = fmaf(w0, __uint_as_float(u0.x << 16),         az[0]);
                az[1] = fmaf(w0, __uint_as_float(u0.x & 0xffff0000u), az[1]);
                az[2] = fmaf(w0, __uint_as_float(u0.y << 16),         az[2]);
                az[3] = fmaf(w0, __uint_as_float(u0.y & 0xffff0000u), az[3]);
                az[4] = fmaf(w0, __uint_as_float(u0.z << 16),         az[4]);
                az[5] = fmaf(w0, __uint_as_float(u0.z & 0xffff0000u), az[5]);
                az[6] = fmaf(w0, __uint_as_float(u0.w << 16),         az[6]);
                az[7] = fmaf(w0, __uint_as_float(u0.w & 0xffff0000u), az[7]);
                az[0] = fmaf(w1, __uint_as_float(u1.x << 16),         az[0]);
                az[1] = fmaf(w1, __uint_as_float(u1.x & 0xffff0000u), az[1]);
                az[2] = fmaf(w1, __uint_as_float(u1.y << 16),         az[2]);
                az[3] = fmaf(w1, __uint_as_float(u1.y & 0xffff0000u), az[3]);
                az[4] = fmaf(w1, __uint_as_float(u1.z << 16),         az[4]);
                az[5] = fmaf(w1, __uint_as_float(u1.z & 0xffff0000u), az[5]);
                az[6] = fmaf(w1, __uint_as_float(u1.w << 16),         az[6]);
                az[7] = fmaf(w1, __uint_as_float(u1.w & 0xffff0000u), az[7]);
                az[0] = fmaf(w2, __uint_as_float(u2.x << 16),         az[0]);
                az[1] = fmaf(w2, __uint_as_float(u2.x & 0xffff0000u), az[1]);
                az[2] = fmaf(w2, __uint_as_float(u2.y << 16),         az[2]);
                az[3] = fmaf(w2, __uint_as_float(u2.y & 0xffff0000u), az[3]);
                az[4] = fmaf(w2, __uint_as_float(u2.z << 16),         az[4]);
                az[5] = fmaf(w2, __uint_as_float(u2.z & 0xffff0000u), az[5]);
                az[6] = fmaf(w2, __uint_as_float(u2.w << 16),         az[6]);
                az[7] = fmaf(w2, __uint_as_float(u2.w & 0xffff0000u), az[7]);
                az[0] = fmaf(w3, __uint_as_float(u3.x << 16),         az[0]);
                az[1] = fmaf(w3, __uint_as_float(u3.x & 0xffff0000u), az[1]);
                az[2] = fmaf(w3, __uint_as_float(u3.y << 16),         az[2]);
                az[3] = fmaf(w3, __uint_as_float(u3.y & 0xffff0000u), az[3]);
                az[4] = fmaf(w3, __uint_as_float(u3.z << 16),         az[4]);
                az[5] = fmaf(w3, __uint_as_float(u3.z & 0xffff0000u), az[5]);
                az[6] = fmaf(w3, __uint_as_float(u3.w << 16),         az[6]);
                az[7] = fmaf(w3, __uint_as_float(u3.w & 0xffff0000u), az[7]);
            }
            // tail
            for (; j < cn; j += 16u) {
                uint2 v = lrec[j];
                unsigned nd = v.x < NN ? v.x : 0u;
                float w = __uint_as_float(v.y);
                uint4 u = xs[(size_t)nd * 16 + l16];
                az[0] = fmaf(w, __uint_as_float(u.x << 16),          az[0]);
                az[1] = fmaf(w, __uint_as_float(u.x & 0xffff0000u),  az[1]);
                az[2] = fmaf(w, __uint_as_float(u.y << 16),          az[2]);
                az[3] = fmaf(w, __uint_as_float(u.y & 0xffff0000u),  az[3]);
                az[4] = fmaf(w, __uint_as_float(u.z << 16),          az[4]);
                az[5] = fmaf(w, __uint_as_float(u.z & 0xffff0000u),  az[5]);
                az[6] = fmaf(w, __uint_as_float(u.w << 16),          az[6]);
                az[7] = fmaf(w, __uint_as_float(u.w & 0xffff0000u),  az[7]);
            }
        }
    }
    // reduce the 4 record-subgroups: lanes 0-15 end with column totals
    #pragma unroll
    for (int k = 0; k < 8; ++k) {
        az[k] += __shfl_xor(az[k], 16);
        az[k] += __shfl_xor(az[k], 32);
    }
    __syncthreads();                  // lrec dead; red reuse safe
    if (wv > 0 && lane < 16) {
        #pragma unroll
        for (int k = 0; k < 8; ++k) red[wv - 1][l16 * 8 + k] = az[k];
    }
    __syncthreads();
    if (wv == 0 && lane < 16) {
        #pragma unroll
        for (int k = 0; k < 8; ++k) {
            float s = az[k] + red[0][l16 * 8 + k] + red[1][l16 * 8 + k] + red[2][l16 * 8 + k];
            part[(size_t)b * KRH + l16 * 8 + k] = s;
        }
    }
}

// out[r][c] = 0.25 * sum_sbin part[r*8+sbin][c]; dtype follows input.
__global__ __launch_bounds__(256) void k_out(const float* __restrict__ part,
                                             const unsigned* __restrict__ flag, void* __restrict__ out) {
    int i = blockIdx.x * 256 + threadIdx.x;
    if (i < NR * KRH) {
        int r = i >> 7, c = i & 127;
        float v = 0.f;
        for (int s = 0; s < NSB; ++s) v += part[(size_t)(r * NSB + s) * KRH + c];
        v *= 0.25f;                   // / num_heads(2) / 2
        if (!isfinite(v)) v = 0.f;
        if (flag[0]) ((__hip_bfloat16*)out)[i] = __float2bfloat16(v);
        else         ((float*)out)[i] = v;
    }
}

extern "C" void kernel_launch(void* const* d_in, const int* in_sizes, int n_in,
                              void* d_out, int out_size, void* d_ws, size_t ws_size,
                              hipStream_t stream) {
    const void* xe  = d_in[0];
    const int* eidx = (const int*)d_in[1];
    const int* rel  = (const int*)d_in[2];
    const void* wh  = d_in[3];
    const void* wt  = d_in[4];
    const void* ahp = d_in[5];
    const void* atp = d_in[6];

    const int* src = eidx;
    const int* dst = eidx + NE;

    char* ws = (char*)d_ws;
    __hip_bfloat16* xh = (__hip_bfloat16*)(ws + OFF_XH);
    __hip_bfloat16* xt = (__hip_bfloat16*)(ws + OFF_XT);
    float4*   sp     = (float4*)(ws + OFF_SP);
    float4*   dp     = (float4*)(ws + OFF_DP);
    float*    sums   = (float*)(ws + OFF_SUMS);
    unsigned* histH  = (unsigned*)(ws + OFF_HISTH);
    unsigned* histT  = (unsigned*)(ws + OFF_HISTT);
    float*    invs   = (float*)(ws + OFF_INVS);
    unsigned* baseH  = (unsigned*)(ws + OFF_BASEH);
    unsigned* baseT  = (unsigned*)(ws + OFF_BASET);
    uint2*    recH   = (uint2*)(ws + OFF_RECH);
    uint2*    recT   = (uint2*)(ws + OFF_RECT);
    float*    partp  = (float*)(ws + OFF_PART);
    float*    ah32   = (float*)(ws + OFF_AH);
    float*    at32   = (float*)(ws + OFF_AT);
    unsigned* flag   = (unsigned*)(ws + OFF_FLAG);
    __bf16*   whh    = (__bf16*)(ws + OFF_WHH);
    __bf16*   wth    = (__bf16*)(ws + OFF_WTH);
    unsigned* hpbH   = (unsigned*)(ws + OFF_HPBH);
    unsigned* hpbT   = (unsigned*)(ws + OFF_HPBT);

    k_init<<<161, 256, 0, stream>>>((const unsigned*)xe, ahp, atp, wh, wt, flag, ah32, at32,
                                     whh, wth, (unsigned*)(ws + OFF_SUMS));
    k_gemm<<<256, 1024, 0, stream>>>(xe, flag, whh, wth, ah32, at32, xh, xt, sp, dp);
    k_edge<<<NBE, 1024, 0, stream>>>(src, dst, rel, sp, dp, sums, histH, histT, hpbH, hpbT);
    k_scan<<<2 * (NBK / CSB), 256, 0, stream>>>(histH, histT, sums, hpbH, hpbT, baseH, baseT, invs);
    k_mkrec<<<NBE, 1024, 0, stream>>>(src, dst, rel, sp, dp, (const float4*)invs, hpbH, hpbT, recH, recT);
    k_accR<<<NBK, 256, 0, stream>>>(recH, recT, baseH, baseT, xh, xt, partp);
    k_out<<<(NR * KRH + 255) / 256, 256, 0, stream>>>(partp, flag, d_out);
}